// Round 6
// baseline (808.175 us; speedup 1.0000x reference)
//
#include <hip/hip_runtime.h>

// Balanced sinkhorn, persistent kernel, round 6.
// R5 post-mortem: reducer blocks double as workers => systematic stragglers;
// stage-1 flag hop redundant. Fixes:
//  - blocks 0..15: DEDICATED reducers (no row tile) parked on stage-2
//  - blocks 16..255: workers, 64x69 + 176x68 rows = 16384
//  - stage 1 flagless: P NaN-sentinel value-poll (bitmask round-robin);
//    workers re-invalidate their parity row after consuming fin (ordering
//    via the vmcnt(0) drains of intervening __syncthreads)
//  - dense slot layout (pair slot at +256) for line-coalesced polls
// Phase math / replicated optimizer identical to R3-R5 (absmax 2.4e-4).

namespace {

constexpr int KDIM = 256;
constexpr int NBLK = 256;
constexpr int NRED = 16;    // dedicated reducer blocks
constexpr int NW   = 240;   // worker blocks
constexpr int RMAX = 69;    // max rows per worker
constexpr float L2E20 = 28.853900817779268f;  // 20 * log2(e)

// ws layout (doubles): P[2][240][512] | fin[2][6][16][512]
constexpr size_t P_DBL   = 2ull * NW * 512;      // 245760
constexpr size_t FIN_OFF = P_DBL;
constexpr size_t FIN_PAR = 6ull * 16 * 512;      // 49152 per parity
constexpr size_t FIN_DBL = 2 * FIN_PAR;          // 98304
constexpr size_t WS_DBL  = P_DBL + FIN_DBL;      // 344064 (2.62 MB)

__device__ __forceinline__ double fast_exp_d(double x) {
  const double LOG2E  = 1.4426950408889634074;
  const double LN2_HI = 6.93147180369123816490e-01;
  const double LN2_LO = 1.90821492927058770002e-10;
  double n = rint(x * LOG2E);
  double t = fma(-n, LN2_HI, x);
  t = fma(-n, LN2_LO, t);
  double p = 2.4801587301587302e-05;
  p = fma(p, t, 1.9841269841269841e-04);
  p = fma(p, t, 1.3888888888888889e-03);
  p = fma(p, t, 8.3333333333333333e-03);
  p = fma(p, t, 4.1666666666666664e-02);
  p = fma(p, t, 1.6666666666666666e-01);
  p = fma(p, t, 0.5);
  p = fma(p, t, 1.0);
  p = fma(p, t, 1.0);
  long long ni = (long long)n;
  double s = __longlong_as_double((unsigned long long)(ni + 1023LL) << 52);
  return p * s;
}

__device__ __forceinline__ double wave_sum_d(double v) {
#pragma unroll
  for (int o = 32; o > 0; o >>= 1) v += __shfl_down(v, o);
  return v;
}
__device__ __forceinline__ double wave_max_d(double v) {
#pragma unroll
  for (int o = 32; o > 0; o >>= 1) v = fmax(v, __shfl_down(v, o));
  return v;
}

__device__ __forceinline__ double pload(const double* p) {
  return __hip_atomic_load(p, __ATOMIC_RELAXED, __HIP_MEMORY_SCOPE_AGENT);
}
__device__ __forceinline__ void pstore(double* p, double v) {
  __hip_atomic_store(p, v, __ATOMIC_RELAXED, __HIP_MEMORY_SCOPE_AGENT);
}

}  // namespace

// ---------------------------------------------------------------------------
__global__ __launch_bounds__(256) void kInitWS(double* __restrict__ ws) {
  const double QN = __builtin_nan("");
  size_t gid = (size_t)blockIdx.x * 256 + threadIdx.x;
  size_t stride = (size_t)gridDim.x * 256;
  for (size_t j = gid; j < WS_DBL; j += stride) ws[j] = QN;
}

// ---------------------------------------------------------------------------
__global__ __launch_bounds__(256, 1) void sink_main(
    const float* __restrict__ feat, const float* __restrict__ w_in,
    float* __restrict__ out, double* __restrict__ ws) {
  __shared__ float  Et[RMAX * KDIM];   // 69 KB
  __shared__ float  Ft[RMAX * KDIM];   // 69 KB
  __shared__ double alpha[KDIM];
  __shared__ double tmp1[KDIM];        // reducer fold
  __shared__ double tmp2[KDIM];
  __shared__ double sfin[32];
  __shared__ double v1s[RMAX], v2s[RMAX], v3s[RMAX];
  __shared__ double grow[RMAX], wrow[RMAX], sbr[RMAX];
  __shared__ float  mrow[RMAX];
  __shared__ double sred[8];

  const int t = threadIdx.x, bid = blockIdx.x;
  const int wv = t >> 6, lane = t & 63;
  const double QN = __builtin_nan("");

  double* P = ws;
  double* fin = ws + FIN_OFF;

  // ======================= REDUCER PATH (blocks 0..15) =====================
  if (bid < NRED) {
    const int rep = t >> 4, c = t & 15;
    const int k = bid * 16 + c;

    auto do_reduce = [&](unsigned ph, int kind, bool pair, int par) {
      const int q = ph & 1;
      // refresh other-parity fin sentinel (consumers done >=1 iter ago)
      if (kind != 0) {
        double* dst = fin + (size_t)(1 - par) * FIN_PAR +
                      (size_t)kind * 8192 + (size_t)rep * 512 + k;
        pstore(dst, QN);
        if (pair) pstore(dst + 256, QN);
      }
      // stage-1: value-poll 15 worker partials for our k
      double a1 = 0.0, a2 = 0.0;
      unsigned m1 = 0x7FFFu, m2 = pair ? 0x7FFFu : 0u;
      while (m1 | m2) {
#pragma unroll
        for (int i = 0; i < 15; ++i) {
          const double* e = P + ((size_t)q * NW + (rep + 16 * i)) * 512 + k;
          if ((m1 >> i) & 1u) {
            double v = pload(e);
            if (!__builtin_isnan(v)) { a1 += v; m1 &= ~(1u << i); }
          }
          if ((m2 >> i) & 1u) {
            double v = pload(e + 256);
            if (!__builtin_isnan(v)) { a2 += v; m2 &= ~(1u << i); }
          }
        }
        if (m1 | m2) __builtin_amdgcn_s_sleep(1);
      }
      tmp1[t] = a1;
      if (pair) tmp2[t] = a2;
      __syncthreads();
      if (t < 16) {
        double s = 0.0;
#pragma unroll
        for (int g = 0; g < 16; ++g) s += tmp1[g * 16 + t];
        sfin[t] = s;
      } else if (pair && t < 32) {
        const int c2 = t - 16;
        double s = 0.0;
#pragma unroll
        for (int g = 0; g < 16; ++g) s += tmp2[g * 16 + c2];
        sfin[16 + c2] = s;
      }
      __syncthreads();
      {
        double* dst = fin + (size_t)par * FIN_PAR + (size_t)kind * 8192 +
                      (size_t)rep * 512 + k;
        pstore(dst, sfin[c]);
        if (pair) pstore(dst + 256, sfin[16 + c]);
      }
      __syncthreads();  // drain fin stores before next round's QN refresh
    };

    unsigned ph = 1;
    do_reduce(ph, 0, false, 0);
    for (int it = 0; it < 9; ++it) {
      const int par = it & 1;
      ++ph; do_reduce(ph, 1, false, par);
      ++ph; do_reduce(ph, 2, false, par);
      ++ph; do_reduce(ph, 3, true,  par);
      ++ph; do_reduce(ph, 4, false, par);
      ++ph; do_reduce(ph, 5, false, par);
    }
    ++ph; do_reduce(ph, 1, false, 1);
    ++ph; do_reduce(ph, 2, false, 1);
    return;
  }

  // ======================= WORKER PATH (blocks 16..255) ====================
  const int wid = bid - NRED;
  const int nr = (wid < 64) ? 69 : 68;
  const int start = (wid < 64) ? wid * 69 : 4416 + (wid - 64) * 68;

  auto blk_sum = [&](double v) -> double {
    v = wave_sum_d(v);
    __syncthreads();
    if (lane == 0) sred[wv] = v;
    __syncthreads();
    return sred[0] + sred[1] + sred[2] + sred[3];
  };
  auto blk_max = [&](double v) -> double {
    v = wave_max_d(v);
    __syncthreads();
    if (lane == 0) sred[wv + 4] = v;
    __syncthreads();
    return fmax(fmax(sred[4], sred[5]), fmax(sred[6], sred[7]));
  };

  // publish partial, consume reduced value (flagless, NaN-sentinel)
  auto w_allreduce = [&](unsigned ph, int kind, bool pair, int par,
                         double pa, double pb, double& r1, double& r2) {
    const int q = ph & 1;
    double* row = P + ((size_t)q * NW + wid) * 512;
    pstore(&row[t], pa);
    if (pair) pstore(&row[256 + t], pb);
    // consume own k=t from own replica
    const double* e = fin + (size_t)par * FIN_PAR + (size_t)kind * 8192 +
                      (size_t)(wid & 15) * 512 + t;
    double a;
    for (;;) {
      a = pload(e);
      if (!__builtin_isnan(a)) break;
      __builtin_amdgcn_s_sleep(1);
    }
    r1 = a;
    if (pair) {
      for (;;) {
        double b2 = pload(e + 256);
        if (!__builtin_isnan(b2)) { r2 = b2; break; }
        __builtin_amdgcn_s_sleep(1);
      }
    }
    __syncthreads();  // all 256 fin entries seen => all reducers done with P[q]
    pstore(&row[t], QN);
    pstore(&row[256 + t], QN);
    // QN drains at the next __syncthreads before any later publish
  };

  auto row_pass = [&](double* dstv) {
    double a0 = alpha[4 * lane + 0], a1 = alpha[4 * lane + 1];
    double a2 = alpha[4 * lane + 2], a3 = alpha[4 * lane + 3];
    for (int r = wv; r < nr; r += 4) {
      float4 e4 = ((const float4*)(Et + r * KDIM))[lane];
      double s1 = a0 * (double)e4.x + a1 * (double)e4.y +
                  a2 * (double)e4.z + a3 * (double)e4.w;
      s1 = wave_sum_d(s1);
      if (lane == 0) dstv[r] = s1;
    }
  };
  auto col_partial = [&]() -> double {
    double a = 0.0;
#pragma unroll 4
    for (int r = 0; r < nr; ++r) a += (double)Et[r * KDIM + t] * wrow[r];
    return a;
  };

  // ---- setup
  {
    const float4* src = (const float4*)(feat + (size_t)start * KDIM);
    float4* dst = (float4*)Ft;
    const int total4 = nr * 64;
    for (int s = t; s < total4; s += 256) dst[s] = src[s];
  }
  __syncthreads();
  for (int r = wv; r < nr; r += 4) {
    float4 f4 = ((const float4*)(Ft + r * KDIM))[lane];
    float m = fmaxf(fmaxf(f4.x, f4.y), fmaxf(f4.z, f4.w));
#pragma unroll
    for (int o = 32; o > 0; o >>= 1) m = fmaxf(m, __shfl_down(m, o));
    if (lane == 0) {
      mrow[r] = m;
      sbr[r] = fast_exp_d(20.0 * (double)m);
    }
  }
  __syncthreads();
  double pu0 = 0.0;
#pragma unroll 4
  for (int r = 0; r < nr; ++r) {
    float e = exp2f((Ft[r * KDIM + t] - mrow[r]) * L2E20);
    Et[r * KDIM + t] = e;
    pu0 += (double)e * sbr[r];
  }
  float w_t = w_in[t], buf_t = 0.0f;
  double k2_t;
  {
    double x = (double)w_t;
    double m = blk_max(x);
    double e = fast_exp_d(x - m);
    double s = blk_sum(e);
    k2_t = e / s;
  }
  unsigned ph = 1;
  double u0_t, dmy;
  w_allreduce(ph, 0, false, 0, pu0, 0.0, u0_t, dmy);

  // ---- outer loop
  for (int it = 0; it < 10; ++it) {
    const int p = it & 1;
    double u1_t, u2_t;

    // A: v1~, allreduce u1
    alpha[t] = k2_t / u0_t;
    __syncthreads();
    row_pass(v1s);
    __syncthreads();
    if (t < nr) wrow[t] = 1.0 / (16384.0 * v1s[t]);
    __syncthreads();
    { double pa = col_partial(); ++ph; w_allreduce(ph, 1, false, p, pa, 0.0, u1_t, dmy); }

    // B: v2~, allreduce u2
    alpha[t] = k2_t / u1_t;
    __syncthreads();
    row_pass(v2s);
    __syncthreads();
    if (t < nr) wrow[t] = 1.0 / (16384.0 * v2s[t]);
    __syncthreads();
    { double pa = col_partial(); ++ph; w_allreduce(ph, 2, false, p, pa, 0.0, u2_t, dmy); }

    if (it == 9) {
      // output: Q[b,k] = alpha3[k]*E~[r,k]/v3~[b]
      alpha[t] = k2_t / u2_t;
      __syncthreads();
      row_pass(v3s);
      __syncthreads();
      if (t < nr) wrow[t] = 1.0 / v3s[t];
      __syncthreads();
      double a3 = alpha[t];
#pragma unroll 4
      for (int r = 0; r < nr; ++r)
        out[(size_t)(start + r) * KDIM + t] =
            (float)(a3 * (double)Et[r * KDIM + t] * wrow[r]);
      return;
    }

    // C: v3~, gv3~; allreduce (gdir, t3)
    alpha[t] = k2_t / u2_t;
    __syncthreads();
    {
      double a0 = alpha[4 * lane + 0], a1 = alpha[4 * lane + 1];
      double a2 = alpha[4 * lane + 2], a3 = alpha[4 * lane + 3];
      for (int r = wv; r < nr; r += 4) {
        float4 e4 = ((const float4*)(Et + r * KDIM))[lane];
        float4 f4 = ((const float4*)(Ft + r * KDIM))[lane];
        double p0 = a0 * (double)e4.x, p1 = a1 * (double)e4.y;
        double p2 = a2 * (double)e4.z, p3 = a3 * (double)e4.w;
        double s1 = p0 + p1 + p2 + p3;
        double s2 = p0 * (double)f4.x + p1 * (double)f4.y +
                    p2 * (double)f4.z + p3 * (double)f4.w;
        s1 = wave_sum_d(s1);
        s2 = wave_sum_d(s2);
        if (lane == 0) {
          v3s[r] = s1;
          grow[r] = s2 / (16384.0 * s1 * s1);  // gv3~
        }
      }
    }
    __syncthreads();
    if (t < nr) wrow[t] = -1.0 / (16384.0 * v3s[t]);
    __syncthreads();
    double gd_t, t3_t;
    {
      double ac1 = 0.0, ac2 = 0.0;
#pragma unroll 4
      for (int r = 0; r < nr; ++r) {
        double ed = (double)Et[r * KDIM + t];
        ac1 += ed * (double)Ft[r * KDIM + t] * wrow[r];
        ac2 += ed * grow[r];
      }
      ++ph; w_allreduce(ph, 3, true, p, ac1, ac2, gd_t, t3_t);
    }

    // D: gu2 -> gv2~; allreduce ga2
    alpha[t] = -(gd_t + t3_t) * k2_t / (u2_t * u2_t);
    __syncthreads();
    row_pass(grow);
    __syncthreads();
    if (t < nr) wrow[t] = -grow[t] / (16384.0 * v2s[t] * v2s[t]);
    __syncthreads();
    double ga2_t;
    { double pa = col_partial(); ++ph; w_allreduce(ph, 4, false, p, pa, 0.0, ga2_t, dmy); }

    // E: gu1 -> gv1~; allreduce ga1
    alpha[t] = -ga2_t * k2_t / (u1_t * u1_t);
    __syncthreads();
    row_pass(grow);
    __syncthreads();
    if (t < nr) wrow[t] = -grow[t] / (16384.0 * v1s[t] * v1s[t]);
    __syncthreads();
    double ga1_t;
    { double pa = col_partial(); ++ph; w_allreduce(ph, 5, false, p, pa, 0.0, ga1_t, dmy); }

    // F: replicated optimizer step (block-local)
    {
      double gk2 = (gd_t + t3_t) / u2_t + ga2_t / u1_t + ga1_t / u0_t;
      double dot = blk_sum(k2_t * gk2);
      double gw = k2_t * (gk2 - dot) + 5.0 * (k2_t / 256.0 - 1.0 / 65536.0);
      double n2 = blk_sum(gw * gw);
      float normf = (float)sqrt(n2);
      float sc = fminf(1.0f, 1.0f / (normf + 1e-6f));
      float g = (float)gw * sc;
      buf_t = 0.99f * buf_t + g;
      w_t = w_t - 0.1f * buf_t;
      double x = (double)w_t;
      double m = blk_max(x);
      double e = fast_exp_d(x - m);
      double s = blk_sum(e);
      k2_t = e / s;
    }
  }
}

// ---------------------------------------------------------------------------
extern "C" void kernel_launch(void* const* d_in, const int* in_sizes, int n_in,
                              void* d_out, int out_size, void* d_ws,
                              size_t ws_size, hipStream_t stream) {
  (void)in_sizes; (void)n_in; (void)out_size; (void)ws_size;
  const float* feat = (const float*)d_in[0];
  const float* w_in = (const float*)d_in[1];
  float* out = (float*)d_out;
  double* ws = (double*)d_ws;

  kInitWS<<<128, 256, 0, stream>>>(ws);
  sink_main<<<NBLK, 256, 0, stream>>>(feat, w_in, out, ws);
}

// Round 7
// 588.829 us; speedup vs baseline: 1.3725x; 1.3725x over previous
//
#include <hip/hip_runtime.h>

// Balanced sinkhorn, persistent kernel, round 7.
// R6 post-mortem: flagless stage-1 value-poll serialized 15 dependent
// NaN-check loads per round (~4-5us) — worse than R5's flag+burst. R7 =
// R6 topology (16 DEDICATED reducer blocks parked on stage-2; 240 workers
// with 68/69 rows) + R5 protocol (flag1 store after vmcnt-drained
// syncthreads; reducer burst-reads 15 independent partials; fin x16
// replicas; consumer NaN value-poll). No P sentinels.
// Phase math / replicated optimizer identical to R3-R6 (absmax 2.4e-4).

namespace {

constexpr int KDIM = 256;
constexpr int NBLK = 256;
constexpr int NRED = 16;    // dedicated reducer blocks
constexpr int NW   = 240;   // worker blocks
constexpr int RMAX = 69;    // max rows per worker
constexpr float L2E20 = 28.853900817779268f;  // 20 * log2(e)

// ws layout (doubles): P[2][240][512] | fin[2][6][16][512] | flag1 (u32)
constexpr size_t P_DBL   = 2ull * NW * 512;      // 245760
constexpr size_t FIN_OFF = P_DBL;
constexpr size_t FIN_PAR = 6ull * 16 * 512;      // 49152 per parity
constexpr size_t FIN_DBL = 2 * FIN_PAR;          // 98304
constexpr size_t FLAG_OFF_DBL = FIN_OFF + FIN_DBL;
constexpr int FLAG_U32 = NW * 32;                // one 128B line per worker

__device__ __forceinline__ double fast_exp_d(double x) {
  const double LOG2E  = 1.4426950408889634074;
  const double LN2_HI = 6.93147180369123816490e-01;
  const double LN2_LO = 1.90821492927058770002e-10;
  double n = rint(x * LOG2E);
  double t = fma(-n, LN2_HI, x);
  t = fma(-n, LN2_LO, t);
  double p = 2.4801587301587302e-05;
  p = fma(p, t, 1.9841269841269841e-04);
  p = fma(p, t, 1.3888888888888889e-03);
  p = fma(p, t, 8.3333333333333333e-03);
  p = fma(p, t, 4.1666666666666664e-02);
  p = fma(p, t, 1.6666666666666666e-01);
  p = fma(p, t, 0.5);
  p = fma(p, t, 1.0);
  p = fma(p, t, 1.0);
  long long ni = (long long)n;
  double s = __longlong_as_double((unsigned long long)(ni + 1023LL) << 52);
  return p * s;
}

__device__ __forceinline__ double wave_sum_d(double v) {
#pragma unroll
  for (int o = 32; o > 0; o >>= 1) v += __shfl_down(v, o);
  return v;
}
__device__ __forceinline__ double wave_max_d(double v) {
#pragma unroll
  for (int o = 32; o > 0; o >>= 1) v = fmax(v, __shfl_down(v, o));
  return v;
}

__device__ __forceinline__ double pload(const double* p) {
  return __hip_atomic_load(p, __ATOMIC_RELAXED, __HIP_MEMORY_SCOPE_AGENT);
}
__device__ __forceinline__ void pstore(double* p, double v) {
  __hip_atomic_store(p, v, __ATOMIC_RELAXED, __HIP_MEMORY_SCOPE_AGENT);
}

}  // namespace

// ---------------------------------------------------------------------------
__global__ __launch_bounds__(256) void kInitWS(double* __restrict__ ws) {
  const double QN = __builtin_nan("");
  size_t gid = (size_t)blockIdx.x * 256 + threadIdx.x;
  size_t stride = (size_t)gridDim.x * 256;
  double* fin = ws + FIN_OFF;
  for (size_t j = gid; j < FIN_DBL; j += stride) fin[j] = QN;
  unsigned* fl = (unsigned*)(ws + FLAG_OFF_DBL);
  if (gid < FLAG_U32) fl[gid] = 0u;
}

// ---------------------------------------------------------------------------
__global__ __launch_bounds__(256, 1) void sink_main(
    const float* __restrict__ feat, const float* __restrict__ w_in,
    float* __restrict__ out, double* __restrict__ ws) {
  __shared__ float  Et[RMAX * KDIM];   // 69 KB
  __shared__ float  Ft[RMAX * KDIM];   // 69 KB
  __shared__ double alpha[KDIM];
  __shared__ double tmp1[KDIM];        // reducer fold
  __shared__ double tmp2[KDIM];
  __shared__ double sfin[32];
  __shared__ double v1s[RMAX], v2s[RMAX], v3s[RMAX];
  __shared__ double grow[RMAX], wrow[RMAX], sbr[RMAX];
  __shared__ float  mrow[RMAX];
  __shared__ double sred[8];

  const int t = threadIdx.x, bid = blockIdx.x;
  const int wv = t >> 6, lane = t & 63;
  const double QN = __builtin_nan("");

  double* P = ws;
  double* fin = ws + FIN_OFF;
  unsigned* flag1 = (unsigned*)(ws + FLAG_OFF_DBL);  // [240][32] u32

  // ======================= REDUCER PATH (blocks 0..15) =====================
  if (bid < NRED) {
    const int rep = t >> 4, c = t & 15;
    const int k = bid * 16 + c;

    auto do_reduce = [&](unsigned ph, int kind, bool pair, int par) {
      const int q = ph & 1;
      // refresh other-parity fin sentinel (all consumers of that copy are
      // >= one full allreduce in the past — see R5/R6 argument)
      if (kind != 0) {
        double* dst = fin + (size_t)(1 - par) * FIN_PAR +
                      (size_t)kind * 8192 + (size_t)rep * 512 + k;
        pstore(dst, QN);
        if (pair) pstore(dst + 256, QN);
      }
      // stage-1 flag wait: thread t polls worker t's flag line (t<240)
      if (t < NW) {
        const unsigned* f = &flag1[t * 32];
        while (__hip_atomic_load(f, __ATOMIC_RELAXED,
                                 __HIP_MEMORY_SCOPE_AGENT) < ph)
          __builtin_amdgcn_s_sleep(1);
      }
      __syncthreads();
      // burst-read 15 partials (independent loads, pipelined)
      const double* base = P + (size_t)q * NW * 512;
      double a1 = 0.0, a2 = 0.0;
#pragma unroll
      for (int i = 0; i < 15; ++i) {
        const double* rr = base + (size_t)(rep + 16 * i) * 512;
        a1 += pload(&rr[k]);
        if (pair) a2 += pload(&rr[k + 256]);
      }
      tmp1[t] = a1;
      if (pair) tmp2[t] = a2;
      __syncthreads();
      if (t < 16) {
        double s = 0.0;
#pragma unroll
        for (int g = 0; g < 16; ++g) s += tmp1[g * 16 + t];
        sfin[t] = s;
      } else if (pair && t < 32) {
        const int c2 = t - 16;
        double s = 0.0;
#pragma unroll
        for (int g = 0; g < 16; ++g) s += tmp2[g * 16 + c2];
        sfin[16 + c2] = s;
      }
      __syncthreads();
      {
        double* dst = fin + (size_t)par * FIN_PAR + (size_t)kind * 8192 +
                      (size_t)rep * 512 + k;
        pstore(dst, sfin[c]);
        if (pair) pstore(dst + 256, sfin[16 + c]);
      }
      __syncthreads();  // drain fin stores before next round
    };

    unsigned ph = 1;
    do_reduce(ph, 0, false, 0);
    for (int it = 0; it < 9; ++it) {
      const int par = it & 1;
      ++ph; do_reduce(ph, 1, false, par);
      ++ph; do_reduce(ph, 2, false, par);
      ++ph; do_reduce(ph, 3, true,  par);
      ++ph; do_reduce(ph, 4, false, par);
      ++ph; do_reduce(ph, 5, false, par);
    }
    ++ph; do_reduce(ph, 1, false, 1);
    ++ph; do_reduce(ph, 2, false, 1);
    return;
  }

  // ======================= WORKER PATH (blocks 16..255) ====================
  const int wid = bid - NRED;
  const int nr = (wid < 64) ? 69 : 68;
  const int start = (wid < 64) ? wid * 69 : 4416 + (wid - 64) * 68;

  auto blk_sum = [&](double v) -> double {
    v = wave_sum_d(v);
    __syncthreads();
    if (lane == 0) sred[wv] = v;
    __syncthreads();
    return sred[0] + sred[1] + sred[2] + sred[3];
  };
  auto blk_max = [&](double v) -> double {
    v = wave_max_d(v);
    __syncthreads();
    if (lane == 0) sred[wv + 4] = v;
    __syncthreads();
    return fmax(fmax(sred[4], sred[5]), fmax(sred[6], sred[7]));
  };

  // publish partial + flag; consume reduced value via fin NaN value-poll
  auto w_allreduce = [&](unsigned ph, int kind, bool pair, int par,
                         double pa, double pb, double& r1, double& r2) {
    const int q = ph & 1;
    double* row = P + ((size_t)q * NW + wid) * 512;
    pstore(&row[t], pa);
    if (pair) pstore(&row[256 + t], pb);
    __syncthreads();  // vmcnt(0) drain: P stores globally visible
    if (t == 0)
      __hip_atomic_store(&flag1[wid * 32], ph, __ATOMIC_RELAXED,
                         __HIP_MEMORY_SCOPE_AGENT);
    // consume own k=t from own replica
    const double* e = fin + (size_t)par * FIN_PAR + (size_t)kind * 8192 +
                      (size_t)(wid & 15) * 512 + t;
    double a;
    for (;;) {
      a = pload(e);
      if (!__builtin_isnan(a)) break;
      __builtin_amdgcn_s_sleep(1);
    }
    r1 = a;
    if (pair) {
      for (;;) {
        double b2 = pload(e + 256);
        if (!__builtin_isnan(b2)) { r2 = b2; break; }
        __builtin_amdgcn_s_sleep(1);
      }
    }
    __syncthreads();
  };

  auto row_pass = [&](double* dstv) {
    double a0 = alpha[4 * lane + 0], a1 = alpha[4 * lane + 1];
    double a2 = alpha[4 * lane + 2], a3 = alpha[4 * lane + 3];
    for (int r = wv; r < nr; r += 4) {
      float4 e4 = ((const float4*)(Et + r * KDIM))[lane];
      double s1 = a0 * (double)e4.x + a1 * (double)e4.y +
                  a2 * (double)e4.z + a3 * (double)e4.w;
      s1 = wave_sum_d(s1);
      if (lane == 0) dstv[r] = s1;
    }
  };
  auto col_partial = [&]() -> double {
    double a = 0.0;
#pragma unroll 4
    for (int r = 0; r < nr; ++r) a += (double)Et[r * KDIM + t] * wrow[r];
    return a;
  };

  // ---- setup
  {
    const float4* src = (const float4*)(feat + (size_t)start * KDIM);
    float4* dst = (float4*)Ft;
    const int total4 = nr * 64;
    for (int s = t; s < total4; s += 256) dst[s] = src[s];
  }
  __syncthreads();
  for (int r = wv; r < nr; r += 4) {
    float4 f4 = ((const float4*)(Ft + r * KDIM))[lane];
    float m = fmaxf(fmaxf(f4.x, f4.y), fmaxf(f4.z, f4.w));
#pragma unroll
    for (int o = 32; o > 0; o >>= 1) m = fmaxf(m, __shfl_down(m, o));
    if (lane == 0) {
      mrow[r] = m;
      sbr[r] = fast_exp_d(20.0 * (double)m);
    }
  }
  __syncthreads();
  double pu0 = 0.0;
#pragma unroll 4
  for (int r = 0; r < nr; ++r) {
    float e = exp2f((Ft[r * KDIM + t] - mrow[r]) * L2E20);
    Et[r * KDIM + t] = e;
    pu0 += (double)e * sbr[r];
  }
  float w_t = w_in[t], buf_t = 0.0f;
  double k2_t;
  {
    double x = (double)w_t;
    double m = blk_max(x);
    double e = fast_exp_d(x - m);
    double s = blk_sum(e);
    k2_t = e / s;
  }
  unsigned ph = 1;
  double u0_t, dmy;
  w_allreduce(ph, 0, false, 0, pu0, 0.0, u0_t, dmy);

  // ---- outer loop
  for (int it = 0; it < 10; ++it) {
    const int p = it & 1;
    double u1_t, u2_t;

    // A: v1~, allreduce u1
    alpha[t] = k2_t / u0_t;
    __syncthreads();
    row_pass(v1s);
    __syncthreads();
    if (t < nr) wrow[t] = 1.0 / (16384.0 * v1s[t]);
    __syncthreads();
    { double pa = col_partial(); ++ph; w_allreduce(ph, 1, false, p, pa, 0.0, u1_t, dmy); }

    // B: v2~, allreduce u2
    alpha[t] = k2_t / u1_t;
    __syncthreads();
    row_pass(v2s);
    __syncthreads();
    if (t < nr) wrow[t] = 1.0 / (16384.0 * v2s[t]);
    __syncthreads();
    { double pa = col_partial(); ++ph; w_allreduce(ph, 2, false, p, pa, 0.0, u2_t, dmy); }

    if (it == 9) {
      // output: Q[b,k] = alpha3[k]*E~[r,k]/v3~[b]
      alpha[t] = k2_t / u2_t;
      __syncthreads();
      row_pass(v3s);
      __syncthreads();
      if (t < nr) wrow[t] = 1.0 / v3s[t];
      __syncthreads();
      double a3 = alpha[t];
#pragma unroll 4
      for (int r = 0; r < nr; ++r)
        out[(size_t)(start + r) * KDIM + t] =
            (float)(a3 * (double)Et[r * KDIM + t] * wrow[r]);
      return;
    }

    // C: v3~, gv3~; allreduce (gdir, t3)
    alpha[t] = k2_t / u2_t;
    __syncthreads();
    {
      double a0 = alpha[4 * lane + 0], a1 = alpha[4 * lane + 1];
      double a2 = alpha[4 * lane + 2], a3 = alpha[4 * lane + 3];
      for (int r = wv; r < nr; r += 4) {
        float4 e4 = ((const float4*)(Et + r * KDIM))[lane];
        float4 f4 = ((const float4*)(Ft + r * KDIM))[lane];
        double p0 = a0 * (double)e4.x, p1 = a1 * (double)e4.y;
        double p2 = a2 * (double)e4.z, p3 = a3 * (double)e4.w;
        double s1 = p0 + p1 + p2 + p3;
        double s2 = p0 * (double)f4.x + p1 * (double)f4.y +
                    p2 * (double)f4.z + p3 * (double)f4.w;
        s1 = wave_sum_d(s1);
        s2 = wave_sum_d(s2);
        if (lane == 0) {
          v3s[r] = s1;
          grow[r] = s2 / (16384.0 * s1 * s1);  // gv3~
        }
      }
    }
    __syncthreads();
    if (t < nr) wrow[t] = -1.0 / (16384.0 * v3s[t]);
    __syncthreads();
    double gd_t, t3_t;
    {
      double ac1 = 0.0, ac2 = 0.0;
#pragma unroll 4
      for (int r = 0; r < nr; ++r) {
        double ed = (double)Et[r * KDIM + t];
        ac1 += ed * (double)Ft[r * KDIM + t] * wrow[r];
        ac2 += ed * grow[r];
      }
      ++ph; w_allreduce(ph, 3, true, p, ac1, ac2, gd_t, t3_t);
    }

    // D: gu2 -> gv2~; allreduce ga2
    alpha[t] = -(gd_t + t3_t) * k2_t / (u2_t * u2_t);
    __syncthreads();
    row_pass(grow);
    __syncthreads();
    if (t < nr) wrow[t] = -grow[t] / (16384.0 * v2s[t] * v2s[t]);
    __syncthreads();
    double ga2_t;
    { double pa = col_partial(); ++ph; w_allreduce(ph, 4, false, p, pa, 0.0, ga2_t, dmy); }

    // E: gu1 -> gv1~; allreduce ga1
    alpha[t] = -ga2_t * k2_t / (u1_t * u1_t);
    __syncthreads();
    row_pass(grow);
    __syncthreads();
    if (t < nr) wrow[t] = -grow[t] / (16384.0 * v1s[t] * v1s[t]);
    __syncthreads();
    double ga1_t;
    { double pa = col_partial(); ++ph; w_allreduce(ph, 5, false, p, pa, 0.0, ga1_t, dmy); }

    // F: replicated optimizer step (block-local)
    {
      double gk2 = (gd_t + t3_t) / u2_t + ga2_t / u1_t + ga1_t / u0_t;
      double dot = blk_sum(k2_t * gk2);
      double gw = k2_t * (gk2 - dot) + 5.0 * (k2_t / 256.0 - 1.0 / 65536.0);
      double n2 = blk_sum(gw * gw);
      float normf = (float)sqrt(n2);
      float sc = fminf(1.0f, 1.0f / (normf + 1e-6f));
      float g = (float)gw * sc;
      buf_t = 0.99f * buf_t + g;
      w_t = w_t - 0.1f * buf_t;
      double x = (double)w_t;
      double m = blk_max(x);
      double e = fast_exp_d(x - m);
      double s = blk_sum(e);
      k2_t = e / s;
    }
  }
}

// ---------------------------------------------------------------------------
extern "C" void kernel_launch(void* const* d_in, const int* in_sizes, int n_in,
                              void* d_out, int out_size, void* d_ws,
                              size_t ws_size, hipStream_t stream) {
  (void)in_sizes; (void)n_in; (void)out_size; (void)ws_size;
  const float* feat = (const float*)d_in[0];
  const float* w_in = (const float*)d_in[1];
  float* out = (float*)d_out;
  double* ws = (double*)d_ws;

  kInitWS<<<128, 256, 0, stream>>>(ws);
  sink_main<<<NBLK, 256, 0, stream>>>(feat, w_in, out, ws);
}